// Round 3
// baseline (2456.460 us; speedup 1.0000x reference)
//
#include <hip/hip_runtime.h>
#include <math.h>

#define BATCH 4
#define NPTS  8192
#define NSAMP 2048
#define KNBR  64
#define EPSF  1e-5f

typedef float v2f __attribute__((ext_vector_type(2)));

// ---------------------------------------------------------------------------
// Kernel 0: transpose weights into ws so MLP reads are contiguous scalar loads
// ---------------------------------------------------------------------------
__global__ void prep_kernel(const float* __restrict__ W1, const float* __restrict__ W2,
                            const float* __restrict__ W3,
                            float* __restrict__ W1t, float* __restrict__ W2t,
                            float* __restrict__ W3t) {
    int t = threadIdx.x;
    for (int i = t; i < 64 * 67; i += 256) { int o = i / 67, c = i % 67; W1t[c * 64 + o] = W1[i]; }
    for (int i = t; i < 64 * 64; i += 256) { int o = i >> 6, c = i & 63; W2t[c * 64 + o] = W2[i]; }
    for (int i = t; i < 128 * 64; i += 256) { int o = i >> 6, c = i & 63; W3t[c * 128 + o] = W3[i]; }
}

// DPP-based wave64 max over a u64 lex key: both 32-bit halves shuffle from the
// same source lane, reconstructing that lane's full key. row_shr 1/2/4/8 +
// row_bcast 15/31 leaves the full wave max in lane 63. bound_ctrl=true
// zero-fills OOB lanes: key 0 has val=+0 and idx=0x7fffffff (impossible idx),
// so it can never displace a real candidate (strict > merge).
#define DPP_KMAX(k, ctrl)                                                              \
    do {                                                                               \
        unsigned lo_ = (unsigned)(k);                                                  \
        unsigned hi_ = (unsigned)((k) >> 32);                                          \
        int slo_ = __builtin_amdgcn_update_dpp(0, (int)lo_, ctrl, 0xf, 0xf, true);     \
        int shi_ = __builtin_amdgcn_update_dpp(0, (int)hi_, ctrl, 0xf, 0xf, true);     \
        unsigned long long ks_ =                                                       \
            ((unsigned long long)(unsigned)shi_ << 32) | (unsigned)slo_;               \
        if (ks_ > (k)) (k) = ks_;                                                      \
    } while (0)

// ---------------------------------------------------------------------------
// Kernel 1: farthest point sampling — one block per batch, 256 threads
// (4 waves, 1/SIMD = minimum machinery duplication), 32 points/thread as 16
// packed fp32 pairs. contract(off) => plain IEEE rn mul/add, bit-identical
// to the numpy ref.
//
// v4: argmax via a monotone u64 key fused INTO the distance loop:
//   key = (dist_bits << 32) | (0x7FFFFFFF - idx)
// dist >= 0 -> float bits are order-monotone as u32, so max-key == max dist
// with ties broken to MINIMUM index — exactly jnp.argmax first-occurrence,
// uniformly at every level (pair / lane / wave / block). This deletes the
// entire post-loop serial tail of v2/v3 (value tree, readlane broadcast,
// ballot/ctz, candidate scan, 2nd readlane): per step the chain is now
//   j-loop -> 3 kacc merges -> 6 DPP-u64 -> publish -> barrier
//   -> read 4 keys -> 3 u64-max -> sp[cur].
// ---------------------------------------------------------------------------
__global__ __launch_bounds__(256, 1) void fps_kernel(const float* __restrict__ x,
                                                     float* __restrict__ cen_out) {
#pragma clang fp contract(off)
    const int b = blockIdx.x;
    const int tid = threadIdx.x;
    const int lane = tid & 63;
    const int wid = tid >> 6;
    __shared__ float4 sp[NPTS];                              // 128 KB packed xyz_
    __shared__ __align__(16) unsigned long long pubk[2][4];  // per-wave max key
    __shared__ int hist[NSAMP];                              // 8 KB

    const float* xb = x + (size_t)b * NPTS * 3;
    for (int i = tid; i < NPTS; i += 256) {
        sp[i] = (float4){xb[3 * i + 0], xb[3 * i + 1], xb[3 * i + 2], 0.f};
    }
    __syncthreads();

    // 32 points/thread as 16 pairs: pair j holds p = tid*32+2j, +1
    v2f px[16], py[16], pz[16], dist[16];
    const int base = tid * 32;
    const unsigned nb = 0x7FFFFFFFu - (unsigned)base;  // key low-word base
#pragma unroll
    for (int j = 0; j < 16; j++) {
        float4 a = sp[base + 2 * j];
        float4 c = sp[base + 2 * j + 1];
        px[j] = (v2f){a.x, c.x};
        py[j] = (v2f){a.y, c.y};
        pz[j] = (v2f){a.z, c.z};
        dist[j] = (v2f){1e10f, 1e10f};
    }

    int cur = 0;
    float4 cp = sp[0];
    for (int s = 0; s < NSAMP; s++) {
        if (tid == 0) hist[s] = cur;
        const v2f cvx = (v2f){cp.x, cp.x}, cvy = (v2f){cp.y, cp.y}, cvz = (v2f){cp.z, cp.z};
        unsigned long long kacc[4] = {0ull, 0ull, 0ull, 0ull};
#pragma unroll
        for (int j = 0; j < 16; j++) {
            v2f dx = px[j] - cvx;
            v2f dy = py[j] - cvy;
            v2f dz = pz[j] - cvz;
            v2f d = ((dx * dx) + (dy * dy)) + (dz * dz);   // contract(off): exact rn
            v2f dm;
            dm.x = fminf(dist[j].x, d.x);
            dm.y = fminf(dist[j].y, d.y);
            dist[j] = dm;
            float t = fmaxf(dm.x, dm.y);                   // fmax returns an operand
            // pair-local winner: x preferred on tie (lower index). Both 2j and
            // 2j+1 are inline constants (<= 31) after unroll.
            unsigned so = (dm.x == t) ? (unsigned)(2 * j) : (unsigned)(2 * j + 1);
            unsigned long long key =
                ((unsigned long long)__float_as_uint(t) << 32) | (nb - so);
            if (key > kacc[j & 3]) kacc[j & 3] = key;      // j&3 static after unroll
        }
        unsigned long long ka = kacc[0] > kacc[1] ? kacc[0] : kacc[1];
        unsigned long long kb = kacc[2] > kacc[3] ? kacc[2] : kacc[3];
        unsigned long long k = ka > kb ? ka : kb;

        // wave-level u64 max via DPP; full max lands in lane 63
        DPP_KMAX(k, 0x111);   // row_shr:1
        DPP_KMAX(k, 0x112);   // row_shr:2
        DPP_KMAX(k, 0x114);   // row_shr:4
        DPP_KMAX(k, 0x118);   // row_shr:8
        DPP_KMAX(k, 0x142);   // row_bcast:15
        DPP_KMAX(k, 0x143);   // row_bcast:31

        const int p = s & 1;
        if (lane == 63) pubk[p][wid] = k;
        __syncthreads();                                   // the ONLY barrier/step

        // cross-wave select: plain u64 max (keys embed idx tie-break exactly)
        unsigned long long q0 = pubk[p][0], q1 = pubk[p][1];
        unsigned long long q2 = pubk[p][2], q3 = pubk[p][3];
        unsigned long long m0 = q0 > q1 ? q0 : q1;
        unsigned long long m1 = q2 > q3 ? q2 : q3;
        unsigned long long kbest = m0 > m1 ? m0 : m1;
        cur = (int)(0x7FFFFFFFu - (unsigned)kbest);
        cp = sp[cur];                                      // one ds_read_b128
    }

    // bulk centroid writeback (one-time; indices -> coords from LDS)
    __syncthreads();
    for (int i = tid; i < NSAMP; i += 256) {
        int idx = hist[i];
        float4 q = sp[idx];
        float* o = cen_out + ((size_t)b * NSAMP + i) * 3;
        o[0] = q.x; o[1] = q.y; o[2] = q.z;
    }
}

// ---------------------------------------------------------------------------
// Kernel 2: ball query — one wave per centroid, ballot compaction, first-K in
// ascending index order (== top_k(-cand) semantics), -1 padded.
// ---------------------------------------------------------------------------
__global__ __launch_bounds__(256) void ball_kernel(const float* __restrict__ x,
                                                   const float* __restrict__ cen,
                                                   int* __restrict__ idxb) {
    const int wid = threadIdx.x >> 6, lane = threadIdx.x & 63;
    const int id = blockIdx.x * 4 + wid;           // 0..8191 == b*NSAMP+s
    const int b = id >> 11;
    const float r2 = (float)(0.2 * 0.2);
    const float cx = cen[3 * id], cy = cen[3 * id + 1], cz = cen[3 * id + 2];
    const float* xb = x + (size_t)b * NPTS * 3;

    int count = 0;
    for (int base = 0; base < NPTS && count < KNBR; base += 64) {
        int p = base + lane;
        float pxv = xb[3 * p], pyv = xb[3 * p + 1], pzv = xb[3 * p + 2];
        float dx = __fsub_rn(cx, pxv);
        float dy = __fsub_rn(cy, pyv);
        float dz = __fsub_rn(cz, pzv);
        float d2 = __fadd_rn(__fadd_rn(__fmul_rn(dx, dx), __fmul_rn(dy, dy)), __fmul_rn(dz, dz));
        bool hit = d2 < r2;
        unsigned long long m = __ballot(hit);
        if (hit) {
            int pos = count + __popcll(m & ((1ull << lane) - 1ull));
            if (pos < KNBR) idxb[(size_t)id * KNBR + pos] = p;
        }
        count += (int)__popcll(m);
    }
    for (int pos = count + lane; pos < KNBR; pos += 64)
        idxb[(size_t)id * KNBR + pos] = -1;
}

// ---------------------------------------------------------------------------
// Kernel 3: gather + 3x(conv1x1+BN+ReLU) + masked max pool.
// One wave per centroid, lane = neighbor. h1/h2 in registers; weights via
// wave-uniform scalar loads (transposed layout). Layer3 in 4 chunks of 32
// channels with per-wave LDS max-reduction across lanes.
// ---------------------------------------------------------------------------
__global__ __launch_bounds__(256) void mlp_kernel(
    const float* __restrict__ x, const float* __restrict__ xc,
    const float* __restrict__ cen, const int* __restrict__ idxb,
    const float* __restrict__ W1t, const float* __restrict__ b1, const float* __restrict__ g1,
    const float* __restrict__ bt1, const float* __restrict__ m1, const float* __restrict__ v1,
    const float* __restrict__ W2t, const float* __restrict__ b2, const float* __restrict__ g2,
    const float* __restrict__ bt2, const float* __restrict__ m2, const float* __restrict__ v2,
    const float* __restrict__ W3t, const float* __restrict__ b3, const float* __restrict__ g3,
    const float* __restrict__ bt3, const float* __restrict__ m3, const float* __restrict__ v3,
    float* __restrict__ pooled) {
    const int wid = threadIdx.x >> 6, lane = threadIdx.x & 63;
    const int id = blockIdx.x * 4 + wid;            // b*NSAMP + s
    const int b = id >> 11;
    __shared__ float sred[4][64][33];

    int il = idxb[(size_t)id * KNBR + lane];
    bool valid = il >= 0;
    int ik = valid ? il : 0;

    float cx = cen[3 * id], cy = cen[3 * id + 1], cz = cen[3 * id + 2];
    const float* xp = x + ((size_t)b * NPTS + ik) * 3;
    const float* xcp = xc + ((size_t)b * NPTS + ik) * 64;

    // ----- layer 1: 67 -> 64 -----
    float h1[64];
#pragma unroll
    for (int o = 0; o < 64; o++) h1[o] = 0.f;
#pragma unroll
    for (int c4 = 0; c4 < 16; c4++) {
        float4 t = ((const float4*)xcp)[c4];
        float tv0 = t.x, tv1 = t.y, tv2 = t.z, tv3 = t.w;
#pragma unroll
        for (int o = 0; o < 64; o++) h1[o] = fmaf(W1t[(c4 * 4 + 0) * 64 + o], tv0, h1[o]);
#pragma unroll
        for (int o = 0; o < 64; o++) h1[o] = fmaf(W1t[(c4 * 4 + 1) * 64 + o], tv1, h1[o]);
#pragma unroll
        for (int o = 0; o < 64; o++) h1[o] = fmaf(W1t[(c4 * 4 + 2) * 64 + o], tv2, h1[o]);
#pragma unroll
        for (int o = 0; o < 64; o++) h1[o] = fmaf(W1t[(c4 * 4 + 3) * 64 + o], tv3, h1[o]);
    }
    {
        float xl0 = xp[0] - cx, xl1 = xp[1] - cy, xl2 = xp[2] - cz;
#pragma unroll
        for (int o = 0; o < 64; o++) h1[o] = fmaf(W1t[64 * 64 + o], xl0, h1[o]);
#pragma unroll
        for (int o = 0; o < 64; o++) h1[o] = fmaf(W1t[65 * 64 + o], xl1, h1[o]);
#pragma unroll
        for (int o = 0; o < 64; o++) h1[o] = fmaf(W1t[66 * 64 + o], xl2, h1[o]);
    }
#pragma unroll
    for (int o = 0; o < 64; o++) {
        float sc = g1[o] * rsqrtf(v1[o] + EPSF);
        h1[o] = fmaxf(fmaf(h1[o] + b1[o] - m1[o], sc, bt1[o]), 0.f);
    }

    // ----- layer 2: 64 -> 64 -----
    float h2[64];
#pragma unroll
    for (int o = 0; o < 64; o++) h2[o] = 0.f;
#pragma unroll
    for (int c = 0; c < 64; c++) {
        float hv = h1[c];
#pragma unroll
        for (int o = 0; o < 64; o++) h2[o] = fmaf(W2t[c * 64 + o], hv, h2[o]);
    }
#pragma unroll
    for (int o = 0; o < 64; o++) {
        float sc = g2[o] * rsqrtf(v2[o] + EPSF);
        h2[o] = fmaxf(fmaf(h2[o] + b2[o] - m2[o], sc, bt2[o]), 0.f);
    }

    // ----- layer 3: 64 -> 128, in 4 chunks of 32, fused masked max-pool -----
    for (int ch = 0; ch < 4; ch++) {
        float acc[32];
#pragma unroll
        for (int oo = 0; oo < 32; oo++) acc[oo] = 0.f;
#pragma unroll
        for (int c = 0; c < 64; c++) {
            float hv = h2[c];
#pragma unroll
            for (int oo = 0; oo < 32; oo++)
                acc[oo] = fmaf(W3t[c * 128 + ch * 32 + oo], hv, acc[oo]);
        }
#pragma unroll
        for (int oo = 0; oo < 32; oo++) {
            int o = ch * 32 + oo;
            float sc = g3[o] * rsqrtf(v3[o] + EPSF);
            float t = fmaxf(fmaf(acc[oo] + b3[o] - m3[o], sc, bt3[o]), 0.f);
            sred[wid][lane][oo] = valid ? t : -INFINITY;
        }
        __syncthreads();
        {
            int c = lane & 31, half = lane >> 5;
            float mx = -INFINITY;
#pragma unroll
            for (int r = 0; r < 32; r++) mx = fmaxf(mx, sred[wid][half * 32 + r][c]);
            mx = fmaxf(mx, __shfl_xor(mx, 32, 64));
            if (lane < 32) pooled[(size_t)id * 128 + ch * 32 + c] = mx;
        }
        __syncthreads();
    }
}

// ---------------------------------------------------------------------------
extern "C" void kernel_launch(void* const* d_in, const int* in_sizes, int n_in,
                              void* d_out, int out_size, void* d_ws, size_t ws_size,
                              hipStream_t stream) {
    const float* x  = (const float*)d_in[0];
    const float* xc = (const float*)d_in[1];
    const float* W1 = (const float*)d_in[2];
    const float* b1 = (const float*)d_in[3];
    const float* g1 = (const float*)d_in[4];
    const float* bt1 = (const float*)d_in[5];
    const float* m1 = (const float*)d_in[6];
    const float* v1 = (const float*)d_in[7];
    const float* W2 = (const float*)d_in[8];
    const float* b2 = (const float*)d_in[9];
    const float* g2 = (const float*)d_in[10];
    const float* bt2 = (const float*)d_in[11];
    const float* m2 = (const float*)d_in[12];
    const float* v2 = (const float*)d_in[13];
    const float* W3 = (const float*)d_in[14];
    const float* b3 = (const float*)d_in[15];
    const float* g3 = (const float*)d_in[16];
    const float* bt3 = (const float*)d_in[17];
    const float* m3 = (const float*)d_in[18];
    const float* v3 = (const float*)d_in[19];

    float* out = (float*)d_out;
    float* cen = out;                                   // [B,S,3]
    float* pooled = out + (size_t)BATCH * NSAMP * 3;    // [B,S,128]

    int* idxb = (int*)d_ws;                             // [B*S, K] = 2 MB
    float* W1t = (float*)((char*)d_ws + (size_t)BATCH * NSAMP * KNBR * 4);
    float* W2t = W1t + 67 * 64;
    float* W3t = W2t + 64 * 64;

    prep_kernel<<<1, 256, 0, stream>>>(W1, W2, W3, W1t, W2t, W3t);
    fps_kernel<<<BATCH, 256, 0, stream>>>(x, cen);
    ball_kernel<<<(BATCH * NSAMP) / 4, 256, 0, stream>>>(x, cen, idxb);
    mlp_kernel<<<(BATCH * NSAMP) / 4, 256, 0, stream>>>(
        x, xc, cen, idxb,
        W1t, b1, g1, bt1, m1, v1,
        W2t, b2, g2, bt2, m2, v2,
        W3t, b3, g3, bt3, m3, v3,
        pooled);
}

// Round 4
// 2424.523 us; speedup vs baseline: 1.0132x; 1.0132x over previous
//
#include <hip/hip_runtime.h>
#include <math.h>

#define BATCH 4
#define NPTS  8192
#define NSAMP 2048
#define KNBR  64
#define EPSF  1e-5f

// ---------------------------------------------------------------------------
// Kernel 0: transpose weights into ws so MLP reads are contiguous scalar loads
// ---------------------------------------------------------------------------
__global__ void prep_kernel(const float* __restrict__ W1, const float* __restrict__ W2,
                            const float* __restrict__ W3,
                            float* __restrict__ W1t, float* __restrict__ W2t,
                            float* __restrict__ W3t) {
    int t = threadIdx.x;
    for (int i = t; i < 64 * 67; i += 256) { int o = i / 67, c = i % 67; W1t[c * 64 + o] = W1[i]; }
    for (int i = t; i < 64 * 64; i += 256) { int o = i >> 6, c = i & 63; W2t[c * 64 + o] = W2[i]; }
    for (int i = t; i < 128 * 64; i += 256) { int o = i >> 6, c = i & 63; W3t[c * 128 + o] = W3[i]; }
}

// DPP-based wave64 float max: row_shr 1/2/4/8 + row_bcast 15/31; full max in
// lane 63. bound_ctrl=true zero-fills — safe for max of non-negative values.
#define DPP_FMAX(v, ctrl)                                                            \
    do {                                                                             \
        int _t = __builtin_amdgcn_update_dpp(0, __float_as_int(v), ctrl, 0xf, 0xf, true); \
        (v) = fmaxf((v), __int_as_float(_t));                                        \
    } while (0)

// ---------------------------------------------------------------------------
// Kernel 1: farthest point sampling — one block per batch, 512 threads
// (8 waves, 2/SIMD so the second wave's issue hides the per-step LDS/DPP
// chain), 16 points/thread, fully scalar fp32. contract(off) => plain IEEE rn
// mul/add, bit-identical to the numpy ref.
//
// v5 (slim-tail): loop is the lean 10-inst/point form (3 sub, 3 mul, 2 add,
// 1 min, 1 max-acc). Tail per wave:
//   value-only DPP max (12 inst) -> readlane(63) broadcast
//   -> ballot/ctz winning lane (SALU)
//   -> flat candidate cmp/select + v_min3 tree (~40 inst, depth 3)
//   -> readlane local idx -> u64 key (valbits<<32 | 8191-idx)
//   -> lane 63 publishes key; ONE barrier; 8-way u64 max (ties embed the
//      min-index rule exactly == jnp.argmax first-occurrence).
// ---------------------------------------------------------------------------
__global__ __launch_bounds__(512, 2) void fps_kernel(const float* __restrict__ x,
                                                     float* __restrict__ cen_out) {
#pragma clang fp contract(off)
    const int tid = threadIdx.x;
    const int lane = tid & 63;
    const int wid = tid >> 6;
    __shared__ float4 sp[NPTS];                              // 128 KB packed xyz_
    __shared__ __align__(16) unsigned long long pub[2][8];   // per-wave max key
    __shared__ int hist[NSAMP];                              // 8 KB

    const float* xb = x + (size_t)blockIdx.x * NPTS * 3;
    for (int i = tid; i < NPTS; i += 512) {
        sp[i] = (float4){xb[3 * i + 0], xb[3 * i + 1], xb[3 * i + 2], 0.f};
    }
    __syncthreads();

    // 16 points/thread, lane-major: thread tid owns [tid*16, tid*16+16).
    // Wave w covers [w*1024,(w+1)*1024) — index order matches (wid,lane,i)
    // order, so every tie-break level composes to global first-occurrence.
    float qx[16], qy[16], qz[16], dist[16];
    const int base = tid * 16;
#pragma unroll
    for (int i = 0; i < 16; i++) {
        float4 a = sp[base + i];
        qx[i] = a.x; qy[i] = a.y; qz[i] = a.z;
        dist[i] = 1e10f;
    }

    int cur = 0;
    float4 cp = sp[0];
    for (int s = 0; s < NSAMP; s++) {
        if (tid == 0) hist[s] = cur;
        const float cx = cp.x, cy = cp.y, cz = cp.z;
        float ta0 = -1.f, ta1 = -1.f, ta2 = -1.f, ta3 = -1.f;
#pragma unroll
        for (int i = 0; i < 16; i++) {
            float dx = qx[i] - cx;
            float dy = qy[i] - cy;
            float dz = qz[i] - cz;
            float d = ((dx * dx) + (dy * dy)) + (dz * dz);   // contract(off): exact rn
            float dm = fminf(dist[i], d);
            dist[i] = dm;
            if ((i & 3) == 0) ta0 = fmaxf(ta0, dm);
            if ((i & 3) == 1) ta1 = fmaxf(ta1, dm);
            if ((i & 3) == 2) ta2 = fmaxf(ta2, dm);
            if ((i & 3) == 3) ta3 = fmaxf(ta3, dm);
        }
        float bestd = fmaxf(fmaxf(ta0, ta1), fmaxf(ta2, ta3));

        // wave value-max via DPP; full max lands in lane 63, broadcast
        float w = bestd;
        DPP_FMAX(w, 0x111);   // row_shr:1
        DPP_FMAX(w, 0x112);   // row_shr:2
        DPP_FMAX(w, 0x114);   // row_shr:4
        DPP_FMAX(w, 0x118);   // row_shr:8
        DPP_FMAX(w, 0x142);   // row_bcast:15
        DPP_FMAX(w, 0x143);   // row_bcast:31
        const float wmax = __int_as_float(__builtin_amdgcn_readlane(__float_as_int(w), 63));

        // winning lane = lowest lane achieving the wave max (== lowest index)
        unsigned long long mask = __ballot(bestd == wmax);
        int wl = (int)__builtin_ctzll(mask);

        // flat candidate select + min3 tree: lowest local i with dist==wmax.
        // (dists >= +0.0, no NaN; fmin/fmax return operands bitwise, so '=='
        //  identifies exactly the elements achieving the max.)
        int c[16];
#pragma unroll
        for (int i = 0; i < 16; i++) c[i] = (dist[i] == wmax) ? i : 0x7fffffff;
        int m0 = min(min(c[0], c[1]), c[2]);
        int m1 = min(min(c[3], c[4]), c[5]);
        int m2 = min(min(c[6], c[7]), c[8]);
        int m3 = min(min(c[9], c[10]), c[11]);
        int m4 = min(min(c[12], c[13]), c[14]);
        int lo5 = min(min(m0, m1), m2);
        int lo6 = min(min(m3, m4), c[15]);
        int lo = min(lo5, lo6);

        // winner's global index and u64 key (monotone: bigger val wins, tie ->
        // bigger low word == smaller index — exact argmax first-occurrence)
        int lwin = __builtin_amdgcn_readlane(lo, wl);
        int widx = (wid << 10) + (wl << 4) + lwin;
        unsigned long long key =
            ((unsigned long long)__float_as_uint(wmax) << 32) |
            (unsigned)(NPTS - 1 - widx);

        const int p = s & 1;
        if (lane == 63) pub[p][wid] = key;
        __syncthreads();                                   // the ONLY barrier/step

        // 8-way u64 max (ties embedded in key)
        unsigned long long q0 = pub[p][0], q1 = pub[p][1];
        unsigned long long q2 = pub[p][2], q3 = pub[p][3];
        unsigned long long q4 = pub[p][4], q5 = pub[p][5];
        unsigned long long q6 = pub[p][6], q7 = pub[p][7];
        unsigned long long a0 = q0 > q1 ? q0 : q1;
        unsigned long long a1 = q2 > q3 ? q2 : q3;
        unsigned long long a2 = q4 > q5 ? q4 : q5;
        unsigned long long a3 = q6 > q7 ? q6 : q7;
        unsigned long long b0 = a0 > a1 ? a0 : a1;
        unsigned long long b1 = a2 > a3 ? a2 : a3;
        unsigned long long kbest = b0 > b1 ? b0 : b1;
        cur = (NPTS - 1) - (int)(unsigned)kbest;
        cp = sp[cur];                                      // one ds_read_b128
    }

    // bulk centroid writeback (one-time; indices -> coords from LDS)
    __syncthreads();
    for (int i = tid; i < NSAMP; i += 512) {
        int idx = hist[i];
        float4 q = sp[idx];
        float* o = cen_out + ((size_t)blockIdx.x * NSAMP + i) * 3;
        o[0] = q.x; o[1] = q.y; o[2] = q.z;
    }
}

// ---------------------------------------------------------------------------
// Kernel 2: ball query — one wave per centroid, ballot compaction, first-K in
// ascending index order (== top_k(-cand) semantics), -1 padded.
// ---------------------------------------------------------------------------
__global__ __launch_bounds__(256) void ball_kernel(const float* __restrict__ x,
                                                   const float* __restrict__ cen,
                                                   int* __restrict__ idxb) {
    const int wid = threadIdx.x >> 6, lane = threadIdx.x & 63;
    const int id = blockIdx.x * 4 + wid;           // 0..8191 == b*NSAMP+s
    const int b = id >> 11;
    const float r2 = (float)(0.2 * 0.2);
    const float cx = cen[3 * id], cy = cen[3 * id + 1], cz = cen[3 * id + 2];
    const float* xb = x + (size_t)b * NPTS * 3;

    int count = 0;
    for (int base = 0; base < NPTS && count < KNBR; base += 64) {
        int p = base + lane;
        float pxv = xb[3 * p], pyv = xb[3 * p + 1], pzv = xb[3 * p + 2];
        float dx = __fsub_rn(cx, pxv);
        float dy = __fsub_rn(cy, pyv);
        float dz = __fsub_rn(cz, pzv);
        float d2 = __fadd_rn(__fadd_rn(__fmul_rn(dx, dx), __fmul_rn(dy, dy)), __fmul_rn(dz, dz));
        bool hit = d2 < r2;
        unsigned long long m = __ballot(hit);
        if (hit) {
            int pos = count + __popcll(m & ((1ull << lane) - 1ull));
            if (pos < KNBR) idxb[(size_t)id * KNBR + pos] = p;
        }
        count += (int)__popcll(m);
    }
    for (int pos = count + lane; pos < KNBR; pos += 64)
        idxb[(size_t)id * KNBR + pos] = -1;
}

// ---------------------------------------------------------------------------
// Kernel 3: gather + 3x(conv1x1+BN+ReLU) + masked max pool.
// One wave per centroid, lane = neighbor. h1/h2 in registers; weights via
// wave-uniform scalar loads (transposed layout). Layer3 in 4 chunks of 32
// channels with per-wave LDS max-reduction across lanes.
// ---------------------------------------------------------------------------
__global__ __launch_bounds__(256) void mlp_kernel(
    const float* __restrict__ x, const float* __restrict__ xc,
    const float* __restrict__ cen, const int* __restrict__ idxb,
    const float* __restrict__ W1t, const float* __restrict__ b1, const float* __restrict__ g1,
    const float* __restrict__ bt1, const float* __restrict__ m1, const float* __restrict__ v1,
    const float* __restrict__ W2t, const float* __restrict__ b2, const float* __restrict__ g2,
    const float* __restrict__ bt2, const float* __restrict__ m2, const float* __restrict__ v2,
    const float* __restrict__ W3t, const float* __restrict__ b3, const float* __restrict__ g3,
    const float* __restrict__ bt3, const float* __restrict__ m3, const float* __restrict__ v3,
    float* __restrict__ pooled) {
    const int wid = threadIdx.x >> 6, lane = threadIdx.x & 63;
    const int id = blockIdx.x * 4 + wid;            // b*NSAMP + s
    const int b = id >> 11;
    __shared__ float sred[4][64][33];

    int il = idxb[(size_t)id * KNBR + lane];
    bool valid = il >= 0;
    int ik = valid ? il : 0;

    float cx = cen[3 * id], cy = cen[3 * id + 1], cz = cen[3 * id + 2];
    const float* xp = x + ((size_t)b * NPTS + ik) * 3;
    const float* xcp = xc + ((size_t)b * NPTS + ik) * 64;

    // ----- layer 1: 67 -> 64 -----
    float h1[64];
#pragma unroll
    for (int o = 0; o < 64; o++) h1[o] = 0.f;
#pragma unroll
    for (int c4 = 0; c4 < 16; c4++) {
        float4 t = ((const float4*)xcp)[c4];
        float tv0 = t.x, tv1 = t.y, tv2 = t.z, tv3 = t.w;
#pragma unroll
        for (int o = 0; o < 64; o++) h1[o] = fmaf(W1t[(c4 * 4 + 0) * 64 + o], tv0, h1[o]);
#pragma unroll
        for (int o = 0; o < 64; o++) h1[o] = fmaf(W1t[(c4 * 4 + 1) * 64 + o], tv1, h1[o]);
#pragma unroll
        for (int o = 0; o < 64; o++) h1[o] = fmaf(W1t[(c4 * 4 + 2) * 64 + o], tv2, h1[o]);
#pragma unroll
        for (int o = 0; o < 64; o++) h1[o] = fmaf(W1t[(c4 * 4 + 3) * 64 + o], tv3, h1[o]);
    }
    {
        float xl0 = xp[0] - cx, xl1 = xp[1] - cy, xl2 = xp[2] - cz;
#pragma unroll
        for (int o = 0; o < 64; o++) h1[o] = fmaf(W1t[64 * 64 + o], xl0, h1[o]);
#pragma unroll
        for (int o = 0; o < 64; o++) h1[o] = fmaf(W1t[65 * 64 + o], xl1, h1[o]);
#pragma unroll
        for (int o = 0; o < 64; o++) h1[o] = fmaf(W1t[66 * 64 + o], xl2, h1[o]);
    }
#pragma unroll
    for (int o = 0; o < 64; o++) {
        float sc = g1[o] * rsqrtf(v1[o] + EPSF);
        h1[o] = fmaxf(fmaf(h1[o] + b1[o] - m1[o], sc, bt1[o]), 0.f);
    }

    // ----- layer 2: 64 -> 64 -----
    float h2[64];
#pragma unroll
    for (int o = 0; o < 64; o++) h2[o] = 0.f;
#pragma unroll
    for (int c = 0; c < 64; c++) {
        float hv = h1[c];
#pragma unroll
        for (int o = 0; o < 64; o++) h2[o] = fmaf(W2t[c * 64 + o], hv, h2[o]);
    }
#pragma unroll
    for (int o = 0; o < 64; o++) {
        float sc = g2[o] * rsqrtf(v2[o] + EPSF);
        h2[o] = fmaxf(fmaf(h2[o] + b2[o] - m2[o], sc, bt2[o]), 0.f);
    }

    // ----- layer 3: 64 -> 128, in 4 chunks of 32, fused masked max-pool -----
    for (int ch = 0; ch < 4; ch++) {
        float acc[32];
#pragma unroll
        for (int oo = 0; oo < 32; oo++) acc[oo] = 0.f;
#pragma unroll
        for (int c = 0; c < 64; c++) {
            float hv = h2[c];
#pragma unroll
            for (int oo = 0; oo < 32; oo++)
                acc[oo] = fmaf(W3t[c * 128 + ch * 32 + oo], hv, acc[oo]);
        }
#pragma unroll
        for (int oo = 0; oo < 32; oo++) {
            int o = ch * 32 + oo;
            float sc = g3[o] * rsqrtf(v3[o] + EPSF);
            float t = fmaxf(fmaf(acc[oo] + b3[o] - m3[o], sc, bt3[o]), 0.f);
            sred[wid][lane][oo] = valid ? t : -INFINITY;
        }
        __syncthreads();
        {
            int c = lane & 31, half = lane >> 5;
            float mx = -INFINITY;
#pragma unroll
            for (int r = 0; r < 32; r++) mx = fmaxf(mx, sred[wid][half * 32 + r][c]);
            mx = fmaxf(mx, __shfl_xor(mx, 32, 64));
            if (lane < 32) pooled[(size_t)id * 128 + ch * 32 + c] = mx;
        }
        __syncthreads();
    }
}

// ---------------------------------------------------------------------------
extern "C" void kernel_launch(void* const* d_in, const int* in_sizes, int n_in,
                              void* d_out, int out_size, void* d_ws, size_t ws_size,
                              hipStream_t stream) {
    const float* x  = (const float*)d_in[0];
    const float* xc = (const float*)d_in[1];
    const float* W1 = (const float*)d_in[2];
    const float* b1 = (const float*)d_in[3];
    const float* g1 = (const float*)d_in[4];
    const float* bt1 = (const float*)d_in[5];
    const float* m1 = (const float*)d_in[6];
    const float* v1 = (const float*)d_in[7];
    const float* W2 = (const float*)d_in[8];
    const float* b2 = (const float*)d_in[9];
    const float* g2 = (const float*)d_in[10];
    const float* bt2 = (const float*)d_in[11];
    const float* m2 = (const float*)d_in[12];
    const float* v2 = (const float*)d_in[13];
    const float* W3 = (const float*)d_in[14];
    const float* b3 = (const float*)d_in[15];
    const float* g3 = (const float*)d_in[16];
    const float* bt3 = (const float*)d_in[17];
    const float* m3 = (const float*)d_in[18];
    const float* v3 = (const float*)d_in[19];

    float* out = (float*)d_out;
    float* cen = out;                                   // [B,S,3]
    float* pooled = out + (size_t)BATCH * NSAMP * 3;    // [B,S,128]

    int* idxb = (int*)d_ws;                             // [B*S, K] = 2 MB
    float* W1t = (float*)((char*)d_ws + (size_t)BATCH * NSAMP * KNBR * 4);
    float* W2t = W1t + 67 * 64;
    float* W3t = W2t + 64 * 64;

    prep_kernel<<<1, 256, 0, stream>>>(W1, W2, W3, W1t, W2t, W3t);
    fps_kernel<<<BATCH, 512, 0, stream>>>(x, cen);
    ball_kernel<<<(BATCH * NSAMP) / 4, 256, 0, stream>>>(x, cen, idxb);
    mlp_kernel<<<(BATCH * NSAMP) / 4, 256, 0, stream>>>(
        x, xc, cen, idxb,
        W1t, b1, g1, bt1, m1, v1,
        W2t, b2, g2, bt2, m2, v2,
        W3t, b3, g3, bt3, m3, v3,
        pooled);
}

// Round 5
// 2313.283 us; speedup vs baseline: 1.0619x; 1.0481x over previous
//
#include <hip/hip_runtime.h>
#include <math.h>

#define BATCH 4
#define NPTS  8192
#define NSAMP 2048
#define KNBR  64
#define EPSF  1e-5f

// ---------------------------------------------------------------------------
// Kernel 0: transpose weights into ws so MLP reads are contiguous scalar loads
// ---------------------------------------------------------------------------
__global__ void prep_kernel(const float* __restrict__ W1, const float* __restrict__ W2,
                            const float* __restrict__ W3,
                            float* __restrict__ W1t, float* __restrict__ W2t,
                            float* __restrict__ W3t) {
    int t = threadIdx.x;
    for (int i = t; i < 64 * 67; i += 256) { int o = i / 67, c = i % 67; W1t[c * 64 + o] = W1[i]; }
    for (int i = t; i < 64 * 64; i += 256) { int o = i >> 6, c = i & 63; W2t[c * 64 + o] = W2[i]; }
    for (int i = t; i < 128 * 64; i += 256) { int o = i >> 6, c = i & 63; W3t[c * 128 + o] = W3[i]; }
}

// DPP-based wave64 max over a u64 lex key: both 32-bit halves shuffle from the
// same source lane, reconstructing that lane's full key. row_shr 1/2/4/8 +
// row_bcast 15/31 leaves the full wave max in lane 63. bound_ctrl=true
// zero-fills OOB lanes: key 0 can never displace a real candidate (strict >).
#define DPP_KMAX(k, ctrl)                                                              \
    do {                                                                               \
        unsigned lo_ = (unsigned)(k);                                                  \
        unsigned hi_ = (unsigned)((k) >> 32);                                          \
        int slo_ = __builtin_amdgcn_update_dpp(0, (int)lo_, ctrl, 0xf, 0xf, true);     \
        int shi_ = __builtin_amdgcn_update_dpp(0, (int)hi_, ctrl, 0xf, 0xf, true);     \
        unsigned long long ks_ =                                                       \
            ((unsigned long long)(unsigned)shi_ << 32) | (unsigned)slo_;               \
        if (ks_ > (k)) (k) = ks_;                                                      \
    } while (0)

__device__ __forceinline__ unsigned spread3(unsigned v) {  // v in [0,8) -> bits 0,3,6
    return (v & 1u) | ((v & 2u) << 2) | ((v & 4u) << 4);
}

// ---------------------------------------------------------------------------
// Kernel 1: farthest point sampling with EXACT spatial pruning.
// One block per batch, 512 threads (8 waves, 2/SIMD).
//
// v6: Morton-binned counting sort (8x8x8 grid, one-time) gives each thread 16
// spatially-local points (tight AABB) and each wave a contiguous octant.
// Per step, a thread skips its distance update iff
//     lb2(c, AABB) >= tau * (1+2e-6)        [tau = its current max dist]
// which guarantees d(i,c) >= dist[i] for all its points even under fp32
// rounding (margin covers <=9 ulp) -> min() is a bitwise no-op -> skip is
// EXACT, no staleness. All computed distances use the reference formula and
// order (contract(off): sub/mul/add rn), so selections are bit-identical.
//
// Argmax via monotone u64 key: (dist_bits<<32) | (8191-orig)<<13 | sorted_pos.
// dist>=0 -> float bits order-monotone; ties -> min original index — exactly
// jnp.argmax first-occurrence, at thread/wave/block level uniformly. The low
// 13 bits index srt[] directly for the next centroid's coords (1 ds_read_b128).
// One barrier per step, parity-buffered publish slots (R1-proven structure).
// ---------------------------------------------------------------------------
__global__ __launch_bounds__(512, 1) void fps_kernel(const float* __restrict__ x,
                                                     float* __restrict__ cen_out) {
#pragma clang fp contract(off)
    const int tid = threadIdx.x;
    const int lane = tid & 63;
    const int wid = tid >> 6;
    __shared__ float4 srt[NPTS];                             // 128 KB: x,y,z,bitcast(orig)
    __shared__ unsigned hcnt[512];                           // 2 KB
    __shared__ unsigned hofs[512];                           // 2 KB
    __shared__ int hist[NSAMP];                              // 8 KB
    __shared__ __align__(16) unsigned long long pub[2][8];   // per-wave max key

    const float* xb = x + (size_t)blockIdx.x * NPTS * 3;

    // ---- one-time: Morton cell histogram -> exclusive scan -> scatter ----
    hcnt[tid] = 0u;
    __syncthreads();
    unsigned mycell[16];
#pragma unroll
    for (int i = 0; i < 16; i++) {
        int g = tid * 16 + i;
        float px = xb[3 * g], py = xb[3 * g + 1], pz = xb[3 * g + 2];
        unsigned ix = (unsigned)min(7, max(0, (int)(px * 8.f)));
        unsigned iy = (unsigned)min(7, max(0, (int)(py * 8.f)));
        unsigned iz = (unsigned)min(7, max(0, (int)(pz * 8.f)));
        unsigned cell = spread3(ix) | (spread3(iy) << 1) | (spread3(iz) << 2);
        mycell[i] = cell;
        atomicAdd(&hcnt[cell], 1u);
    }
    __syncthreads();
    {
        unsigned own = hcnt[tid];
        for (int d = 1; d < 512; d <<= 1) {
            unsigned t = (tid >= d) ? hcnt[tid - d] : 0u;
            __syncthreads();
            hcnt[tid] += t;
            __syncthreads();
        }
        hofs[tid] = hcnt[tid] - own;   // exclusive prefix
    }
    __syncthreads();
#pragma unroll
    for (int i = 0; i < 16; i++) {
        int g = tid * 16 + i;
        unsigned pos = atomicAdd(&hofs[mycell[i]], 1u);
        srt[pos] = (float4){xb[3 * g], xb[3 * g + 1], xb[3 * g + 2], __int_as_float(g)};
    }
    __syncthreads();

    // ---- load 16 sorted points/thread, AABB, per-point encoded id ----
    float qx[16], qy[16], qz[16], dist[16];
    unsigned pe[16];
#pragma unroll
    for (int i = 0; i < 16; i++) {
        float4 a = srt[tid * 16 + i];
        qx[i] = a.x; qy[i] = a.y; qz[i] = a.z;
        dist[i] = 1e10f;
        unsigned orig = (unsigned)__float_as_int(a.w);
        pe[i] = (((unsigned)(NPTS - 1) - orig) << 13) | (unsigned)(tid * 16 + i);
    }
    float lox = qx[0], hix = qx[0], loy = qy[0], hiy = qy[0], loz = qz[0], hiz = qz[0];
#pragma unroll
    for (int i = 1; i < 16; i++) {
        lox = fminf(lox, qx[i]); hix = fmaxf(hix, qx[i]);
        loy = fminf(loy, qy[i]); hiy = fmaxf(hiy, qy[i]);
        loz = fminf(loz, qz[i]); hiz = fmaxf(hiz, qz[i]);
    }

    float tau = 1e10f;
    unsigned long long myKey = 0ull;
    int cur = 0;
    float cx = xb[0], cy = xb[1], cz = xb[2];

    for (int s = 0; s < NSAMP; s++) {
        if (tid == 0) hist[s] = cur;
        // conservative lower bound of d(c, any owned point): clamp c to AABB
        float bx = cx - fminf(fmaxf(cx, lox), hix);
        float by = cy - fminf(fmaxf(cy, loy), hiy);
        float bz = cz - fminf(fmaxf(cz, loz), hiz);
        float lb2 = ((bx * bx) + (by * by)) + (bz * bz);
        if (lb2 < tau * 1.000002f) {
            // exact update (reference arithmetic: sub, mul, add-x+y, add-z, min)
#pragma unroll
            for (int i = 0; i < 16; i++) {
                float dx = qx[i] - cx;
                float dy = qy[i] - cy;
                float dz = qz[i] - cz;
                float d = ((dx * dx) + (dy * dy)) + (dz * dz);
                dist[i] = fminf(dist[i], d);
            }
            // thread max (fmax returns an operand bitwise)
            float u0 = fmaxf(dist[0], dist[1]),  u1 = fmaxf(dist[2], dist[3]);
            float u2 = fmaxf(dist[4], dist[5]),  u3 = fmaxf(dist[6], dist[7]);
            float u4 = fmaxf(dist[8], dist[9]),  u5 = fmaxf(dist[10], dist[11]);
            float u6 = fmaxf(dist[12], dist[13]), u7 = fmaxf(dist[14], dist[15]);
            float v0 = fmaxf(u0, u1), v1 = fmaxf(u2, u3);
            float v2 = fmaxf(u4, u5), v3 = fmaxf(u6, u7);
            tau = fmaxf(fmaxf(v0, v1), fmaxf(v2, v3));
            // best = max encoded id among maxima (enc is index-inverted ->
            // max enc == min original index: exact first-occurrence tie-break)
            unsigned f0 = 0u, f1 = 0u, f2 = 0u, f3 = 0u;
#pragma unroll
            for (int i = 0; i < 16; i += 4) {
                f0 = max(f0, (dist[i + 0] == tau) ? pe[i + 0] : 0u);
                f1 = max(f1, (dist[i + 1] == tau) ? pe[i + 1] : 0u);
                f2 = max(f2, (dist[i + 2] == tau) ? pe[i + 2] : 0u);
                f3 = max(f3, (dist[i + 3] == tau) ? pe[i + 3] : 0u);
            }
            unsigned fe = max(max(f0, f1), max(f2, f3));
            myKey = ((unsigned long long)__float_as_uint(tau) << 32) |
                    (unsigned long long)fe;
        }

        // wave-level u64 key max via DPP; full max lands in lane 63
        unsigned long long k = myKey;
        DPP_KMAX(k, 0x111);   // row_shr:1
        DPP_KMAX(k, 0x112);   // row_shr:2
        DPP_KMAX(k, 0x114);   // row_shr:4
        DPP_KMAX(k, 0x118);   // row_shr:8
        DPP_KMAX(k, 0x142);   // row_bcast:15
        DPP_KMAX(k, 0x143);   // row_bcast:31

        const int p = s & 1;
        if (lane == 63) pub[p][wid] = k;
        __syncthreads();                                   // the ONLY barrier/step

        unsigned long long q0 = pub[p][0], q1 = pub[p][1];
        unsigned long long q2 = pub[p][2], q3 = pub[p][3];
        unsigned long long q4 = pub[p][4], q5 = pub[p][5];
        unsigned long long q6 = pub[p][6], q7 = pub[p][7];
        unsigned long long a0 = q0 > q1 ? q0 : q1;
        unsigned long long a1 = q2 > q3 ? q2 : q3;
        unsigned long long a2 = q4 > q5 ? q4 : q5;
        unsigned long long a3 = q6 > q7 ? q6 : q7;
        unsigned long long b0 = a0 > a1 ? a0 : a1;
        unsigned long long b1 = a2 > a3 ? a2 : a3;
        unsigned long long kbest = b0 > b1 ? b0 : b1;

        unsigned pos = (unsigned)kbest & 0x1FFFu;               // sorted slot
        cur = (NPTS - 1) - (int)((kbest >> 13) & 0x1FFFull);    // original index
        float4 a = srt[pos];                                    // one ds_read_b128
        cx = a.x; cy = a.y; cz = a.z;
    }

    // bulk centroid writeback (indices -> coords from global; one-time)
    __syncthreads();
    for (int i = tid; i < NSAMP; i += 512) {
        int idx = hist[i];
        float* o = cen_out + ((size_t)blockIdx.x * NSAMP + i) * 3;
        o[0] = xb[3 * idx]; o[1] = xb[3 * idx + 1]; o[2] = xb[3 * idx + 2];
    }
}

// ---------------------------------------------------------------------------
// Kernel 2: ball query — one wave per centroid, ballot compaction, first-K in
// ascending index order (== top_k(-cand) semantics), -1 padded.
// ---------------------------------------------------------------------------
__global__ __launch_bounds__(256) void ball_kernel(const float* __restrict__ x,
                                                   const float* __restrict__ cen,
                                                   int* __restrict__ idxb) {
    const int wid = threadIdx.x >> 6, lane = threadIdx.x & 63;
    const int id = blockIdx.x * 4 + wid;           // 0..8191 == b*NSAMP+s
    const int b = id >> 11;
    const float r2 = (float)(0.2 * 0.2);
    const float cx = cen[3 * id], cy = cen[3 * id + 1], cz = cen[3 * id + 2];
    const float* xb = x + (size_t)b * NPTS * 3;

    int count = 0;
    for (int base = 0; base < NPTS && count < KNBR; base += 64) {
        int p = base + lane;
        float pxv = xb[3 * p], pyv = xb[3 * p + 1], pzv = xb[3 * p + 2];
        float dx = __fsub_rn(cx, pxv);
        float dy = __fsub_rn(cy, pyv);
        float dz = __fsub_rn(cz, pzv);
        float d2 = __fadd_rn(__fadd_rn(__fmul_rn(dx, dx), __fmul_rn(dy, dy)), __fmul_rn(dz, dz));
        bool hit = d2 < r2;
        unsigned long long m = __ballot(hit);
        if (hit) {
            int pos = count + __popcll(m & ((1ull << lane) - 1ull));
            if (pos < KNBR) idxb[(size_t)id * KNBR + pos] = p;
        }
        count += (int)__popcll(m);
    }
    for (int pos = count + lane; pos < KNBR; pos += 64)
        idxb[(size_t)id * KNBR + pos] = -1;
}

// ---------------------------------------------------------------------------
// Kernel 3: gather + 3x(conv1x1+BN+ReLU) + masked max pool.
// One wave per centroid, lane = neighbor. h1/h2 in registers; weights via
// wave-uniform scalar loads (transposed layout). Layer3 in 4 chunks of 32
// channels with per-wave LDS max-reduction across lanes.
// ---------------------------------------------------------------------------
__global__ __launch_bounds__(256) void mlp_kernel(
    const float* __restrict__ x, const float* __restrict__ xc,
    const float* __restrict__ cen, const int* __restrict__ idxb,
    const float* __restrict__ W1t, const float* __restrict__ b1, const float* __restrict__ g1,
    const float* __restrict__ bt1, const float* __restrict__ m1, const float* __restrict__ v1,
    const float* __restrict__ W2t, const float* __restrict__ b2, const float* __restrict__ g2,
    const float* __restrict__ bt2, const float* __restrict__ m2, const float* __restrict__ v2,
    const float* __restrict__ W3t, const float* __restrict__ b3, const float* __restrict__ g3,
    const float* __restrict__ bt3, const float* __restrict__ m3, const float* __restrict__ v3,
    float* __restrict__ pooled) {
    const int wid = threadIdx.x >> 6, lane = threadIdx.x & 63;
    const int id = blockIdx.x * 4 + wid;            // b*NSAMP + s
    const int b = id >> 11;
    __shared__ float sred[4][64][33];

    int il = idxb[(size_t)id * KNBR + lane];
    bool valid = il >= 0;
    int ik = valid ? il : 0;

    float cx = cen[3 * id], cy = cen[3 * id + 1], cz = cen[3 * id + 2];
    const float* xp = x + ((size_t)b * NPTS + ik) * 3;
    const float* xcp = xc + ((size_t)b * NPTS + ik) * 64;

    // ----- layer 1: 67 -> 64 -----
    float h1[64];
#pragma unroll
    for (int o = 0; o < 64; o++) h1[o] = 0.f;
#pragma unroll
    for (int c4 = 0; c4 < 16; c4++) {
        float4 t = ((const float4*)xcp)[c4];
        float tv0 = t.x, tv1 = t.y, tv2 = t.z, tv3 = t.w;
#pragma unroll
        for (int o = 0; o < 64; o++) h1[o] = fmaf(W1t[(c4 * 4 + 0) * 64 + o], tv0, h1[o]);
#pragma unroll
        for (int o = 0; o < 64; o++) h1[o] = fmaf(W1t[(c4 * 4 + 1) * 64 + o], tv1, h1[o]);
#pragma unroll
        for (int o = 0; o < 64; o++) h1[o] = fmaf(W1t[(c4 * 4 + 2) * 64 + o], tv2, h1[o]);
#pragma unroll
        for (int o = 0; o < 64; o++) h1[o] = fmaf(W1t[(c4 * 4 + 3) * 64 + o], tv3, h1[o]);
    }
    {
        float xl0 = xp[0] - cx, xl1 = xp[1] - cy, xl2 = xp[2] - cz;
#pragma unroll
        for (int o = 0; o < 64; o++) h1[o] = fmaf(W1t[64 * 64 + o], xl0, h1[o]);
#pragma unroll
        for (int o = 0; o < 64; o++) h1[o] = fmaf(W1t[65 * 64 + o], xl1, h1[o]);
#pragma unroll
        for (int o = 0; o < 64; o++) h1[o] = fmaf(W1t[66 * 64 + o], xl2, h1[o]);
    }
#pragma unroll
    for (int o = 0; o < 64; o++) {
        float sc = g1[o] * rsqrtf(v1[o] + EPSF);
        h1[o] = fmaxf(fmaf(h1[o] + b1[o] - m1[o], sc, bt1[o]), 0.f);
    }

    // ----- layer 2: 64 -> 64 -----
    float h2[64];
#pragma unroll
    for (int o = 0; o < 64; o++) h2[o] = 0.f;
#pragma unroll
    for (int c = 0; c < 64; c++) {
        float hv = h1[c];
#pragma unroll
        for (int o = 0; o < 64; o++) h2[o] = fmaf(W2t[c * 64 + o], hv, h2[o]);
    }
#pragma unroll
    for (int o = 0; o < 64; o++) {
        float sc = g2[o] * rsqrtf(v2[o] + EPSF);
        h2[o] = fmaxf(fmaf(h2[o] + b2[o] - m2[o], sc, bt2[o]), 0.f);
    }

    // ----- layer 3: 64 -> 128, in 4 chunks of 32, fused masked max-pool -----
    for (int ch = 0; ch < 4; ch++) {
        float acc[32];
#pragma unroll
        for (int oo = 0; oo < 32; oo++) acc[oo] = 0.f;
#pragma unroll
        for (int c = 0; c < 64; c++) {
            float hv = h2[c];
#pragma unroll
            for (int oo = 0; oo < 32; oo++)
                acc[oo] = fmaf(W3t[c * 128 + ch * 32 + oo], hv, acc[oo]);
        }
#pragma unroll
        for (int oo = 0; oo < 32; oo++) {
            int o = ch * 32 + oo;
            float sc = g3[o] * rsqrtf(v3[o] + EPSF);
            float t = fmaxf(fmaf(acc[oo] + b3[o] - m3[o], sc, bt3[o]), 0.f);
            sred[wid][lane][oo] = valid ? t : -INFINITY;
        }
        __syncthreads();
        {
            int c = lane & 31, half = lane >> 5;
            float mx = -INFINITY;
#pragma unroll
            for (int r = 0; r < 32; r++) mx = fmaxf(mx, sred[wid][half * 32 + r][c]);
            mx = fmaxf(mx, __shfl_xor(mx, 32, 64));
            if (lane < 32) pooled[(size_t)id * 128 + ch * 32 + c] = mx;
        }
        __syncthreads();
    }
}

// ---------------------------------------------------------------------------
extern "C" void kernel_launch(void* const* d_in, const int* in_sizes, int n_in,
                              void* d_out, int out_size, void* d_ws, size_t ws_size,
                              hipStream_t stream) {
    const float* x  = (const float*)d_in[0];
    const float* xc = (const float*)d_in[1];
    const float* W1 = (const float*)d_in[2];
    const float* b1 = (const float*)d_in[3];
    const float* g1 = (const float*)d_in[4];
    const float* bt1 = (const float*)d_in[5];
    const float* m1 = (const float*)d_in[6];
    const float* v1 = (const float*)d_in[7];
    const float* W2 = (const float*)d_in[8];
    const float* b2 = (const float*)d_in[9];
    const float* g2 = (const float*)d_in[10];
    const float* bt2 = (const float*)d_in[11];
    const float* m2 = (const float*)d_in[12];
    const float* v2 = (const float*)d_in[13];
    const float* W3 = (const float*)d_in[14];
    const float* b3 = (const float*)d_in[15];
    const float* g3 = (const float*)d_in[16];
    const float* bt3 = (const float*)d_in[17];
    const float* m3 = (const float*)d_in[18];
    const float* v3 = (const float*)d_in[19];

    float* out = (float*)d_out;
    float* cen = out;                                   // [B,S,3]
    float* pooled = out + (size_t)BATCH * NSAMP * 3;    // [B,S,128]

    int* idxb = (int*)d_ws;                             // [B*S, K] = 2 MB
    float* W1t = (float*)((char*)d_ws + (size_t)BATCH * NSAMP * KNBR * 4);
    float* W2t = W1t + 67 * 64;
    float* W3t = W2t + 64 * 64;

    prep_kernel<<<1, 256, 0, stream>>>(W1, W2, W3, W1t, W2t, W3t);
    fps_kernel<<<BATCH, 512, 0, stream>>>(x, cen);
    ball_kernel<<<(BATCH * NSAMP) / 4, 256, 0, stream>>>(x, cen, idxb);
    mlp_kernel<<<(BATCH * NSAMP) / 4, 256, 0, stream>>>(
        x, xc, cen, idxb,
        W1t, b1, g1, bt1, m1, v1,
        W2t, b2, g2, bt2, m2, v2,
        W3t, b3, g3, bt3, m3, v3,
        pooled);
}